// Round 1
// baseline (271.617 us; speedup 1.0000x reference)
//
#include <hip/hip_runtime.h>
#include <math.h>

#define EPSV 1e-6f
constexpr int N_ = 900, B_ = 8, C_ = 256, H_ = 8, D_ = 32;
constexpr int ROWS = 32;
constexpr int R_TOT = N_ * B_;   // 7200 rows for every GEMM

// ---------------------------------------------------------------------------
// Projection GEMM: out_row = X_row @ W^T + bias  (+pos) (sigmoid) (+resid)
// MODE 0: q proj  (pos, sigmoid)        -> qbuf[(b*N+n)*C + c]
// MODE 1: k proj  (pos, sigmoid)        -> kbuf[(b*N+l)*C + c]
// MODE 2: v proj  (no pos, no sigmoid)  -> vbuf[(b*N+l)*C + c]
// MODE 3: out proj (resid=query)        -> d_out[r*C + c], X rows scrambled
// Row index r = seq*B + b  (matches (seq,B,C) row-major layout).
// ---------------------------------------------------------------------------
template<int MODE>
__global__ __launch_bounds__(256)
void proj_kernel(const float* __restrict__ X, const float* __restrict__ W,
                 const float* __restrict__ bias, const float* __restrict__ pos,
                 const float* __restrict__ resid, float* __restrict__ out)
{
    __shared__ float xs[ROWS][C_ + 4];
    const int tid = threadIdx.x;
    const int r0  = blockIdx.x * ROWS;

    // stage 32 input rows into LDS (coalesced: thread tid loads column tid)
    for (int i = 0; i < ROWS; ++i) {
        const int r = r0 + i;
        const float* row;
        if (MODE == 3) {
            const int b = r & 7, n = r >> 3;
            row = X + (size_t)b * (N_ * C_) + (size_t)n * C_;  // scrambled A layout
        } else {
            row = X + (size_t)r * C_;
        }
        xs[i][tid] = row[tid];
    }
    __syncthreads();

    float acc[ROWS];
    #pragma unroll
    for (int i = 0; i < ROWS; ++i) acc[i] = 0.f;

    const float* Wrow = W + (size_t)tid * C_;   // thread owns output column tid
    for (int j = 0; j < C_; j += 4) {
        const float4 wv = *reinterpret_cast<const float4*>(Wrow + j);
        #pragma unroll
        for (int i = 0; i < ROWS; ++i) {
            const float4 xv = *reinterpret_cast<const float4*>(&xs[i][j]);
            acc[i] = fmaf(xv.x, wv.x, acc[i]);
            acc[i] = fmaf(xv.y, wv.y, acc[i]);
            acc[i] = fmaf(xv.z, wv.z, acc[i]);
            acc[i] = fmaf(xv.w, wv.w, acc[i]);
        }
    }

    const float bv = bias[tid];
    #pragma unroll
    for (int i = 0; i < ROWS; ++i) {
        const int r = r0 + i;
        const int b = r & 7, n = r >> 3;
        float v = acc[i] + bv;
        if (MODE == 0 || MODE == 1) {
            v += pos[(size_t)r * C_ + tid];
            v = 1.f / (1.f + expf(-v));          // sigmoid
        }
        if (MODE == 3) {
            v += resid[(size_t)r * C_ + tid];    // residual: query
            out[(size_t)r * C_ + tid] = v;       // (N,B,C) layout
        } else {
            out[((size_t)b * N_ + n) * C_ + tid] = v;  // (B,seq,C) layout
        }
    }
}

// ---------------------------------------------------------------------------
// Per-location head-axis linear attention.  One block = one (b,n) location.
// tid = h*32 + d.  All cumsums are over the HEAD axis (8 steps).
// ---------------------------------------------------------------------------
__device__ __forceinline__ float red32(float v) {
    #pragma unroll
    for (int m = 16; m >= 1; m >>= 1) v += __shfl_xor(v, m, 32);
    return v;   // sum over the 32-lane group (the D axis)
}

__global__ __launch_bounds__(256)
void attn_kernel(const float* __restrict__ qb, const float* __restrict__ kb,
                 const float* __restrict__ vb, float* __restrict__ ab)
{
    const int loc = blockIdx.x;              // b*N + n
    const int b = loc / N_, n = loc % N_;
    const int tid = threadIdx.x;
    const int h = tid >> 5, d = tid & 31;

    __shared__ float q_s[C_], k_s[C_], v_s[C_];
    __shared__ float so8[H_], si8[H_], cs8[H_], sc8[H_];

    const float qv = qb[(size_t)loc * C_ + tid];
    const float kv = kb[(size_t)loc * C_ + tid];
    const float vv = vb[(size_t)loc * C_ + tid];
    q_s[tid] = qv; k_s[tid] = kv; v_s[tid] = vv;
    __syncthreads();

    // cumsum over heads of k and q (per d)
    float ck = 0.f, cq = 0.f;
    for (int h2 = 0; h2 <= h; ++h2) { ck += k_s[h2*32 + d]; cq += q_s[h2*32 + d]; }

    const float normal = (float)(h + 1);
    const float si = normal / red32((qv + EPSV) * (ck + EPSV));  // sink_incoming*normal
    const float so = normal / red32((kv + EPSV) * (cq + EPSV));  // source_outgoing*normal
    if (d == 0) { so8[h] = so; si8[h] = si; }
    __syncthreads();

    // cumsum over heads of k*so and q*si (per d)
    float c2 = 0.f, c3 = 0.f;
    for (int h2 = 0; h2 <= h; ++h2) {
        c2 += k_s[h2*32 + d] * so8[h2];
        c3 += q_s[h2*32 + d] * si8[h2];
    }
    const float consink = red32((qv + EPSV) * (c2 + EPSV)) / normal;
    float consrc        = red32((kv + EPSV) * (c3 + EPSV)) / normal;
    consrc = fminf(1.f, fmaxf(-1.f, consrc));
    const float cs = expf(consrc);
    if (d == 0) cs8[h] = cs;
    __syncthreads();

    float cum = 0.f;
    for (int h2 = 0; h2 <= h; ++h2) cum += cs8[h2];
    const float scomp = cs / cum * normal;     // source_competition
    if (d == 0) sc8[h] = scomp;
    __syncthreads();

    // qkv[h,m] = sum_{h'<=h} (qs[h]·k[h']) * (v[h',m]*sc[h'])   (m = d here)
    const float qs = qv * si / normal;
    float acc = 0.f;
    for (int h2 = 0; h2 <= h; ++h2) {
        const float S = red32(qs * k_s[h2*32 + d]);
        acc += S * v_s[h2*32 + d] * sc8[h2];
    }

    const float salloc = 1.f / (1.f + expf(-consink));  // sigmoid(conserved_sink)
    // store in (B, H, N, D) flat layout -> output GEMM reads rows contiguously
    ab[(size_t)b * (N_*C_) + (size_t)h * (N_*D_) + (size_t)n * D_ + d] = acc * salloc;
}

// ---------------------------------------------------------------------------
extern "C" void kernel_launch(void* const* d_in, const int* in_sizes, int n_in,
                              void* d_out, int out_size, void* d_ws, size_t ws_size,
                              hipStream_t stream)
{
    const float* query = (const float*)d_in[0];
    const float* key   = (const float*)d_in[1];
    const float* qpos  = (const float*)d_in[2];
    const float* kpos  = (const float*)d_in[3];
    const float* Wq = (const float*)d_in[4];  const float* bq = (const float*)d_in[5];
    const float* Wk = (const float*)d_in[6];  const float* bk = (const float*)d_in[7];
    const float* Wv = (const float*)d_in[8];  const float* bv = (const float*)d_in[9];
    const float* Wo = (const float*)d_in[10]; const float* bo = (const float*)d_in[11];

    float* ws   = (float*)d_ws;
    const size_t SZ = (size_t)B_ * N_ * C_;     // 1,843,200 elements each
    float* qbuf = ws;
    float* kbuf = qbuf + SZ;
    float* vbuf = kbuf + SZ;
    float* abuf = vbuf + SZ;
    float* out  = (float*)d_out;

    const dim3 blk(256);
    const int gemm_blocks = R_TOT / ROWS;       // 225

    proj_kernel<0><<<gemm_blocks, blk, 0, stream>>>(query, Wq, bq, qpos, nullptr, qbuf);
    proj_kernel<1><<<gemm_blocks, blk, 0, stream>>>(key,   Wk, bk, kpos, nullptr, kbuf);
    proj_kernel<2><<<gemm_blocks, blk, 0, stream>>>(key,   Wv, bv, nullptr, nullptr, vbuf);
    attn_kernel<<<B_ * N_, blk, 0, stream>>>(qbuf, kbuf, vbuf, abuf);
    proj_kernel<3><<<gemm_blocks, blk, 0, stream>>>(abuf,  Wo, bo, nullptr, query, out);
}

// Round 2
// 78.029 us; speedup vs baseline: 3.4810x; 3.4810x over previous
//
#include <hip/hip_runtime.h>
#include <math.h>

#define EPSV 1e-6f
constexpr int N_ = 900, B_ = 8, C_ = 256, H_ = 8, D_ = 32;
constexpr int M_TOT = N_ * B_;            // 7200 GEMM rows
constexpr int BM = 64, BN = 64;
constexpr int MB = (M_TOT + BM - 1) / BM; // 113 row-blocks

typedef __attribute__((ext_vector_type(8))) short short8;   // 8 bf16 = 4 VGPRs
typedef __attribute__((ext_vector_type(4))) float f32x4;

__device__ __forceinline__ unsigned short f2bf(float f) {   // RNE fp32->bf16
    unsigned int u = __float_as_uint(f);
    unsigned int r = (u + 0x7FFFu + ((u >> 16) & 1u)) >> 16;
    return (unsigned short)r;
}

// swizzled byte offset inside a 64x256-bf16 LDS tile (row stride 512B).
// XOR of bits 4..6 with row&7 spreads same-column rows across 8 16B slots.
__device__ __forceinline__ int swz(int row, int kElem) {
    int b = (row << 9) + (kElem << 1);
    return b ^ ((row & 7) << 4);
}

// ---------------------------------------------------------------------------
// MFMA projection GEMM: out = X @ W^T + bias (+pos, sigmoid | +resid)
// OUTP=false: blockIdx.z = mode 0(q)/1(k)/2(v);  OUTP=true: out-projection.
// ---------------------------------------------------------------------------
template<bool OUTP>
__global__ __launch_bounds__(256)
void proj_mfma(const float* __restrict__ query, const float* __restrict__ key,
               const float* __restrict__ abuf,
               const float* __restrict__ Wq, const float* __restrict__ Wk,
               const float* __restrict__ Wv, const float* __restrict__ Wo,
               const float* __restrict__ bq, const float* __restrict__ bk,
               const float* __restrict__ bv, const float* __restrict__ bo,
               const float* __restrict__ qpos, const float* __restrict__ kpos,
               float* __restrict__ qb, float* __restrict__ kb,
               float* __restrict__ vb, float* __restrict__ outp)
{
    const int mode = OUTP ? 3 : blockIdx.z;
    const float *X, *W, *bias, *pos; float* out;
    if (mode == 0)      { X = query; W = Wq; bias = bq; pos = qpos;    out = qb;   }
    else if (mode == 1) { X = key;   W = Wk; bias = bk; pos = kpos;    out = kb;   }
    else if (mode == 2) { X = key;   W = Wv; bias = bv; pos = nullptr; out = vb;   }
    else                { X = abuf;  W = Wo; bias = bo; pos = nullptr; out = outp; }

    __shared__ unsigned char lds[65536];
    unsigned char* As = lds;          // 64 rows x 512B (bf16, swizzled)
    unsigned char* Bs = lds + 32768;

    const int tid = threadIdx.x;
    const int r0 = blockIdx.x * BM;
    const int c0 = blockIdx.y * BN;

    // ---- stage A (X rows, fp32->bf16) and B (W rows = output cols) ----
    {
        const int trow = tid >> 5;         // 0..7
        const int k0   = (tid & 31) * 8;   // 0..248, 8 floats per thread
        for (int i = 0; i < 8; ++i) {
            const int row = trow + i * 8;  // 0..63
            // A
            const int gr = r0 + row;
            float4 a0, a1;
            if (gr < M_TOT) {
                const float* xr;
                if (mode == 3) { const int b = gr & 7, n = gr >> 3;
                                 xr = X + ((size_t)b * N_ + n) * C_; }
                else           { xr = X + (size_t)gr * C_; }
                a0 = *reinterpret_cast<const float4*>(xr + k0);
                a1 = *reinterpret_cast<const float4*>(xr + k0 + 4);
            } else { a0 = make_float4(0.f,0.f,0.f,0.f); a1 = a0; }
            short8 pa;
            pa[0]=(short)f2bf(a0.x); pa[1]=(short)f2bf(a0.y);
            pa[2]=(short)f2bf(a0.z); pa[3]=(short)f2bf(a0.w);
            pa[4]=(short)f2bf(a1.x); pa[5]=(short)f2bf(a1.y);
            pa[6]=(short)f2bf(a1.z); pa[7]=(short)f2bf(a1.w);
            *reinterpret_cast<short8*>(As + swz(row, k0)) = pa;
            // B
            const float* wr = W + (size_t)(c0 + row) * C_;
            const float4 b0 = *reinterpret_cast<const float4*>(wr + k0);
            const float4 b1 = *reinterpret_cast<const float4*>(wr + k0 + 4);
            short8 pb;
            pb[0]=(short)f2bf(b0.x); pb[1]=(short)f2bf(b0.y);
            pb[2]=(short)f2bf(b0.z); pb[3]=(short)f2bf(b0.w);
            pb[4]=(short)f2bf(b1.x); pb[5]=(short)f2bf(b1.y);
            pb[6]=(short)f2bf(b1.z); pb[7]=(short)f2bf(b1.w);
            *reinterpret_cast<short8*>(Bs + swz(row, k0)) = pb;
        }
    }
    __syncthreads();

    // ---- compute: wave -> 32x32 tile = 2x2 frags of 16x16, K=256 ----
    const int wave = tid >> 6, lane = tid & 63;
    const int wr = (wave >> 1) * 32, wc = (wave & 1) * 32;
    const int lrow = lane & 15;
    const int kgrp = (lane >> 4) * 8;

    f32x4 acc[2][2] = {};
    #pragma unroll
    for (int kk = 0; kk < C_; kk += 32) {
        short8 af[2], bf[2];
        #pragma unroll
        for (int f = 0; f < 2; ++f) {
            af[f] = *reinterpret_cast<const short8*>(As + swz(wr + f*16 + lrow, kk + kgrp));
            bf[f] = *reinterpret_cast<const short8*>(Bs + swz(wc + f*16 + lrow, kk + kgrp));
        }
        #pragma unroll
        for (int i = 0; i < 2; ++i)
            #pragma unroll
            for (int j = 0; j < 2; ++j)
                acc[i][j] = __builtin_amdgcn_mfma_f32_16x16x32_bf16(af[i], bf[j], acc[i][j], 0, 0, 0);
    }

    // ---- epilogue: C/D layout col=lane&15, row=(lane>>4)*4+reg (m89) ----
    const int crow0 = (lane >> 4) * 4;
    const int ccol  = lane & 15;
    #pragma unroll
    for (int i = 0; i < 2; ++i) {
        #pragma unroll
        for (int j = 0; j < 2; ++j) {
            const int gc = c0 + wc + j*16 + ccol;
            const float bias_v = bias[gc];
            #pragma unroll
            for (int r = 0; r < 4; ++r) {
                const int gr = r0 + wr + i*16 + crow0 + r;
                if (gr >= M_TOT) continue;
                float v = acc[i][j][r] + bias_v;
                if (mode <= 1) { v += pos[(size_t)gr * C_ + gc];
                                 v = 1.f / (1.f + expf(-v)); }
                if (mode == 3) {
                    v += query[(size_t)gr * C_ + gc];        // residual
                    out[(size_t)gr * C_ + gc] = v;           // (N,B,C)
                } else {
                    const int b = gr & 7, n = gr >> 3;
                    out[((size_t)b * N_ + n) * C_ + gc] = v; // (B,seq,C)
                }
            }
        }
    }
}

// ---------------------------------------------------------------------------
// Per-location head-axis linear attention (unchanged from passing round 0).
// ---------------------------------------------------------------------------
__device__ __forceinline__ float red32(float v) {
    #pragma unroll
    for (int m = 16; m >= 1; m >>= 1) v += __shfl_xor(v, m, 32);
    return v;
}

__global__ __launch_bounds__(256)
void attn_kernel(const float* __restrict__ qb, const float* __restrict__ kb,
                 const float* __restrict__ vb, float* __restrict__ ab)
{
    const int loc = blockIdx.x;              // b*N + n
    const int b = loc / N_, n = loc % N_;
    const int tid = threadIdx.x;
    const int h = tid >> 5, d = tid & 31;

    __shared__ float q_s[C_], k_s[C_], v_s[C_];
    __shared__ float so8[H_], si8[H_], cs8[H_], sc8[H_];

    const float qv = qb[(size_t)loc * C_ + tid];
    const float kv = kb[(size_t)loc * C_ + tid];
    const float vv = vb[(size_t)loc * C_ + tid];
    q_s[tid] = qv; k_s[tid] = kv; v_s[tid] = vv;
    __syncthreads();

    float ck = 0.f, cq = 0.f;
    for (int h2 = 0; h2 <= h; ++h2) { ck += k_s[h2*32 + d]; cq += q_s[h2*32 + d]; }

    const float normal = (float)(h + 1);
    const float si = normal / red32((qv + EPSV) * (ck + EPSV));
    const float so = normal / red32((kv + EPSV) * (cq + EPSV));
    if (d == 0) { so8[h] = so; si8[h] = si; }
    __syncthreads();

    float c2 = 0.f, c3 = 0.f;
    for (int h2 = 0; h2 <= h; ++h2) {
        c2 += k_s[h2*32 + d] * so8[h2];
        c3 += q_s[h2*32 + d] * si8[h2];
    }
    const float consink = red32((qv + EPSV) * (c2 + EPSV)) / normal;
    float consrc        = red32((kv + EPSV) * (c3 + EPSV)) / normal;
    consrc = fminf(1.f, fmaxf(-1.f, consrc));
    const float cs = expf(consrc);
    if (d == 0) cs8[h] = cs;
    __syncthreads();

    float cum = 0.f;
    for (int h2 = 0; h2 <= h; ++h2) cum += cs8[h2];
    const float scomp = cs / cum * normal;
    if (d == 0) sc8[h] = scomp;
    __syncthreads();

    const float qs = qv * si / normal;
    float acc = 0.f;
    for (int h2 = 0; h2 <= h; ++h2) {
        const float S = red32(qs * k_s[h2*32 + d]);
        acc += S * v_s[h2*32 + d] * sc8[h2];
    }

    const float salloc = 1.f / (1.f + expf(-consink));
    ab[(size_t)b * (N_*C_) + (size_t)h * (N_*D_) + (size_t)n * D_ + d] = acc * salloc;
}

// ---------------------------------------------------------------------------
extern "C" void kernel_launch(void* const* d_in, const int* in_sizes, int n_in,
                              void* d_out, int out_size, void* d_ws, size_t ws_size,
                              hipStream_t stream)
{
    const float* query = (const float*)d_in[0];
    const float* key   = (const float*)d_in[1];
    const float* qpos  = (const float*)d_in[2];
    const float* kpos  = (const float*)d_in[3];
    const float* Wq = (const float*)d_in[4];  const float* bq = (const float*)d_in[5];
    const float* Wk = (const float*)d_in[6];  const float* bk = (const float*)d_in[7];
    const float* Wv = (const float*)d_in[8];  const float* bv = (const float*)d_in[9];
    const float* Wo = (const float*)d_in[10]; const float* bo = (const float*)d_in[11];

    float* ws   = (float*)d_ws;
    const size_t SZ = (size_t)B_ * N_ * C_;
    float* qbuf = ws;
    float* kbuf = qbuf + SZ;
    float* vbuf = kbuf + SZ;
    float* abuf = vbuf + SZ;
    float* out  = (float*)d_out;

    const dim3 blk(256);
    proj_mfma<false><<<dim3(MB, C_/BN, 3), blk, 0, stream>>>(
        query, key, nullptr, Wq, Wk, Wv, nullptr, bq, bk, bv, nullptr,
        qpos, kpos, qbuf, kbuf, vbuf, nullptr);
    attn_kernel<<<B_ * N_, blk, 0, stream>>>(qbuf, kbuf, vbuf, abuf);
    proj_mfma<true><<<dim3(MB, C_/BN, 1), blk, 0, stream>>>(
        query, key, abuf, nullptr, nullptr, nullptr, Wo, nullptr, nullptr, nullptr, bo,
        nullptr, nullptr, nullptr, nullptr, nullptr, out);
}

// Round 4
// 53.214 us; speedup vs baseline: 5.1043x; 1.4663x over previous
//
#include <hip/hip_runtime.h>
#include <math.h>

#define EPSV 1e-6f
constexpr int N_ = 900, B_ = 8, C_ = 256, H_ = 8, D_ = 32;
constexpr int M_TOT = N_ * B_;        // 7200 rows
constexpr int BM = 32;
constexpr int NBLK = M_TOT / BM;      // 225 blocks, exact

typedef __attribute__((ext_vector_type(8))) short short8;       // 8 bf16
typedef __attribute__((ext_vector_type(4))) float f32x4;
typedef __attribute__((ext_vector_type(4))) unsigned short us4;

__device__ __forceinline__ unsigned short f2bf(float f) {   // RNE fp32->bf16
    unsigned int u = __float_as_uint(f);
    return (unsigned short)((u + 0x7FFFu + ((u >> 16) & 1u)) >> 16);
}
// swizzled byte offset in a 32x256-bf16 LDS tile (row stride 512B)
__device__ __forceinline__ int swz(int row, int kElem) {
    int b = (row << 9) + (kElem << 1);
    return b ^ ((row & 7) << 4);
}
__device__ __forceinline__ float red8(float v) {   // sum over 8-lane group
    v += __shfl_xor(v, 1); v += __shfl_xor(v, 2); v += __shfl_xor(v, 4);
    return v;
}

// ---------------------------------------------------------------------------
// prep: pack Wq|Wk|Wv|Wo (fp32 row-major 256x256) -> bf16, concatenated.
// ---------------------------------------------------------------------------
__global__ __launch_bounds__(256)
void pack_w(const float* __restrict__ Wq, const float* __restrict__ Wk,
            const float* __restrict__ Wv, const float* __restrict__ Wo,
            unsigned short* __restrict__ wbf)
{
    const int i = (blockIdx.x * 256 + threadIdx.x) * 8;
    const float* src = (i < 65536) ? Wq : (i < 131072) ? Wk : (i < 196608) ? Wv : Wo;
    const int off = i & 65535;
    const float4 a = *reinterpret_cast<const float4*>(src + off);
    const float4 b = *reinterpret_cast<const float4*>(src + off + 4);
    short8 p;
    p[0]=(short)f2bf(a.x); p[1]=(short)f2bf(a.y); p[2]=(short)f2bf(a.z); p[3]=(short)f2bf(a.w);
    p[4]=(short)f2bf(b.x); p[5]=(short)f2bf(b.y); p[6]=(short)f2bf(b.z); p[7]=(short)f2bf(b.w);
    *reinterpret_cast<short8*>(wbf + i) = p;
}

// ---------------------------------------------------------------------------
// 32-row x 256-col GEMM helper: A from swizzled LDS (bf16), B = W bf16 from
// global (L2-hot). Wave owns 64 cols. K=256 fully unrolled.
// ---------------------------------------------------------------------------
__device__ __forceinline__ void gemm32(const unsigned char* As,
                                       const unsigned short* Wg,
                                       int cw, int lrow, int kg8,
                                       f32x4 acc[2][4])
{
    #pragma unroll
    for (int kk = 0; kk < C_; kk += 32) {
        const short8 af0 = *reinterpret_cast<const short8*>(As + swz(lrow,      kk + kg8));
        const short8 af1 = *reinterpret_cast<const short8*>(As + swz(16 + lrow, kk + kg8));
        #pragma unroll
        for (int j = 0; j < 4; ++j) {
            const short8 bf = *reinterpret_cast<const short8*>(
                Wg + (size_t)(cw + j*16 + lrow) * C_ + kk + kg8);
            acc[0][j] = __builtin_amdgcn_mfma_f32_16x16x32_bf16(af0, bf, acc[0][j], 0, 0, 0);
            acc[1][j] = __builtin_amdgcn_mfma_f32_16x16x32_bf16(af1, bf, acc[1][j], 0, 0, 0);
        }
    }
}

// ---------------------------------------------------------------------------
// Kernel 1: fused q/k/v projections + head-axis attention.
// Writes attn output as bf16 in flat (B,H,N,D) layout: b*230400+h*28800+n*32+d
// (this flat layout IS the reference's swapaxes(1,2).reshape scramble).
// ---------------------------------------------------------------------------
constexpr int QS = 264;                       // fp32 LDS row stride (floats)
constexpr int LDS1 = 16384*2 + 3 * BM * QS * 4;   // 134144 bytes

__global__ __launch_bounds__(256)
void fused_qkva(const float* __restrict__ query, const float* __restrict__ key,
                const float* __restrict__ qpos,  const float* __restrict__ kpos,
                const unsigned short* __restrict__ wbf,
                const float* __restrict__ bq, const float* __restrict__ bk,
                const float* __restrict__ bv,
                unsigned short* __restrict__ abf)
{
    extern __shared__ char smem[];
    unsigned char* Aq = (unsigned char*)smem;            // 16 KB
    unsigned char* Ak = (unsigned char*)smem + 16384;    // 16 KB
    float* q_s = (float*)(smem + 32768);                 // [32][264]
    float* k_s = (float*)(smem + 32768 + 33792);
    float* v_s = (float*)(smem + 32768 + 67584);

    const int tid = threadIdx.x;
    const int r0  = blockIdx.x * BM;

    // ---- phase 0: stage query/key rows -> bf16 swizzled LDS ----
    {
        const int trow = tid >> 5, k0 = (tid & 31) * 8;
        #pragma unroll
        for (int i = 0; i < 4; ++i) {
            const int row = trow + i * 8;
            const float* xr = query + (size_t)(r0 + row) * C_ + k0;
            const float4 a0 = *reinterpret_cast<const float4*>(xr);
            const float4 a1 = *reinterpret_cast<const float4*>(xr + 4);
            short8 pa;
            pa[0]=(short)f2bf(a0.x); pa[1]=(short)f2bf(a0.y);
            pa[2]=(short)f2bf(a0.z); pa[3]=(short)f2bf(a0.w);
            pa[4]=(short)f2bf(a1.x); pa[5]=(short)f2bf(a1.y);
            pa[6]=(short)f2bf(a1.z); pa[7]=(short)f2bf(a1.w);
            *reinterpret_cast<short8*>(Aq + swz(row, k0)) = pa;
            const float* kr = key + (size_t)(r0 + row) * C_ + k0;
            const float4 b0 = *reinterpret_cast<const float4*>(kr);
            const float4 b1 = *reinterpret_cast<const float4*>(kr + 4);
            short8 pb;
            pb[0]=(short)f2bf(b0.x); pb[1]=(short)f2bf(b0.y);
            pb[2]=(short)f2bf(b0.z); pb[3]=(short)f2bf(b0.w);
            pb[4]=(short)f2bf(b1.x); pb[5]=(short)f2bf(b1.y);
            pb[6]=(short)f2bf(b1.z); pb[7]=(short)f2bf(b1.w);
            *reinterpret_cast<short8*>(Ak + swz(row, k0)) = pb;
        }
    }
    __syncthreads();

    const int wave = tid >> 6, lane = tid & 63;
    const int cw = wave * 64;
    const int lrow = lane & 15, kg8 = (lane >> 4) * 8;
    const int crow0 = (lane >> 4) * 4, ccol = lane & 15;

    // ---- phase 1: q/k/v GEMMs -> LDS fp32 (sigmoid on q,k) ----
    {
        f32x4 acc[2][4] = {};
        gemm32(Aq, wbf + 0*65536, cw, lrow, kg8, acc);
        #pragma unroll
        for (int j = 0; j < 4; ++j) {
            const int ch = cw + j*16 + ccol;
            const float bias_v = bq[ch];
            #pragma unroll
            for (int i = 0; i < 2; ++i)
                #pragma unroll
                for (int r = 0; r < 4; ++r) {
                    const int row = i*16 + crow0 + r;
                    float v = acc[i][j][r] + bias_v + qpos[(size_t)(r0+row)*C_ + ch];
                    q_s[row*QS + ch] = 1.f / (1.f + expf(-v));
                }
        }
    }
    {
        f32x4 acc[2][4] = {};
        gemm32(Ak, wbf + 1*65536, cw, lrow, kg8, acc);
        #pragma unroll
        for (int j = 0; j < 4; ++j) {
            const int ch = cw + j*16 + ccol;
            const float bias_v = bk[ch];
            #pragma unroll
            for (int i = 0; i < 2; ++i)
                #pragma unroll
                for (int r = 0; r < 4; ++r) {
                    const int row = i*16 + crow0 + r;
                    float v = acc[i][j][r] + bias_v + kpos[(size_t)(r0+row)*C_ + ch];
                    k_s[row*QS + ch] = 1.f / (1.f + expf(-v));
                }
        }
    }
    {
        f32x4 acc[2][4] = {};
        gemm32(Ak, wbf + 2*65536, cw, lrow, kg8, acc);
        #pragma unroll
        for (int j = 0; j < 4; ++j) {
            const int ch = cw + j*16 + ccol;
            const float bias_v = bv[ch];
            #pragma unroll
            for (int i = 0; i < 2; ++i)
                #pragma unroll
                for (int r = 0; r < 4; ++r) {
                    const int row = i*16 + crow0 + r;
                    v_s[row*QS + ch] = acc[i][j][r] + bias_v;
                }
        }
    }
    __syncthreads();

    // ---- phase 2: per-location head-axis attention (8 threads/location) ----
    {
        const int loc = tid >> 3, tt = tid & 7, d0 = tt * 4;
        const int gr = r0 + loc;                 // global row in (n,b) order
        const int nn = gr >> 3, bb = gr & 7;
        const float* qr = q_s + loc * QS + d0;
        const float* kr = k_s + loc * QS + d0;
        const float* vr = v_s + loc * QS + d0;
        f32x4 qh[8], kh[8], vh[8];
        #pragma unroll
        for (int h = 0; h < 8; ++h) {
            qh[h] = *reinterpret_cast<const f32x4*>(qr + h*32);
            kh[h] = *reinterpret_cast<const f32x4*>(kr + h*32);
            vh[h] = *reinterpret_cast<const f32x4*>(vr + h*32);
        }

        float ir1[8], so_[8];
        {
            f32x4 ck = {0,0,0,0}, cq = {0,0,0,0};
            #pragma unroll
            for (int h = 0; h < 8; ++h) {
                float p1 = 0.f, p2 = 0.f;
                #pragma unroll
                for (int j = 0; j < 4; ++j) {
                    ck[j] += kh[h][j]; cq[j] += qh[h][j];
                    p1 += (qh[h][j] + EPSV) * (ck[j] + EPSV);
                    p2 += (kh[h][j] + EPSV) * (cq[j] + EPSV);
                }
                p1 = red8(p1); p2 = red8(p2);
                ir1[h] = 1.f / p1;
                so_[h] = (float)(h+1) / p2;
            }
        }
        float salloc[8], scomp[8];
        {
            f32x4 c2 = {0,0,0,0}, c3 = {0,0,0,0};
            float css = 0.f;
            #pragma unroll
            for (int h = 0; h < 8; ++h) {
                const float sih = (float)(h+1) * ir1[h];
                float p3 = 0.f, p4 = 0.f;
                #pragma unroll
                for (int j = 0; j < 4; ++j) {
                    c2[j] += kh[h][j] * so_[h];
                    c3[j] += qh[h][j] * sih;
                    p3 += (qh[h][j] + EPSV) * (c2[j] + EPSV);
                    p4 += (kh[h][j] + EPSV) * (c3[j] + EPSV);
                }
                p3 = red8(p3); p4 = red8(p4);
                const float inv_n = 1.f / (float)(h+1);
                salloc[h] = 1.f / (1.f + expf(-p3 * inv_n));
                const float consrc = fminf(1.f, fmaxf(-1.f, p4 * inv_n));
                const float cs = expf(consrc);
                css += cs;
                scomp[h] = cs / css * (float)(h+1);
            }
        }
        // qkv + store to global flat (B,H,N,D) as bf16
        #pragma unroll
        for (int h = 0; h < 8; ++h) {
            f32x4 qs4, a4 = {0,0,0,0};
            #pragma unroll
            for (int j = 0; j < 4; ++j) qs4[j] = qh[h][j] * ir1[h];
            #pragma unroll
            for (int h2 = 0; h2 <= h; ++h2) {
                float p = 0.f;
                #pragma unroll
                for (int j = 0; j < 4; ++j) p += qs4[j] * kh[h2][j];
                p = red8(p);
                const float w = p * scomp[h2];
                #pragma unroll
                for (int j = 0; j < 4; ++j) a4[j] += w * vh[h2][j];
            }
            us4 o;
            #pragma unroll
            for (int j = 0; j < 4; ++j) o[j] = f2bf(a4[j] * salloc[h]);
            *reinterpret_cast<us4*>(abf + (size_t)bb*(H_*N_*D_) + (size_t)h*(N_*D_)
                                        + (size_t)nn*D_ + d0) = o;
        }
    }
}

// ---------------------------------------------------------------------------
// Kernel 2: out-projection + residual. A rows are the SCRAMBLED flat slices
// of abf: output row gr=(n*B+b) reads abf[b*N*C + n*256 .. +255] (bf16).
// ---------------------------------------------------------------------------
__global__ __launch_bounds__(256)
void outproj(const unsigned short* __restrict__ abf,
             const unsigned short* __restrict__ wbf,
             const float* __restrict__ bo,
             const float* __restrict__ query,
             float* __restrict__ out)
{
    __shared__ unsigned char As[16384];
    const int tid = threadIdx.x;
    const int r0  = blockIdx.x * BM;

    {   // stage scrambled A rows (pure bf16 copy)
        const int trow = tid >> 5, k0 = (tid & 31) * 8;
        #pragma unroll
        for (int i = 0; i < 4; ++i) {
            const int row = trow + i * 8;
            const int gr = r0 + row;
            const int nn = gr >> 3, bb = gr & 7;
            const short8 p = *reinterpret_cast<const short8*>(
                abf + (size_t)bb * (N_*C_) + (size_t)nn * C_ + k0);
            *reinterpret_cast<short8*>(As + swz(row, k0)) = p;
        }
    }
    __syncthreads();

    const int wave = tid >> 6, lane = tid & 63;
    const int cw = wave * 64;
    const int lrow = lane & 15, kg8 = (lane >> 4) * 8;
    const int crow0 = (lane >> 4) * 4, ccol = lane & 15;

    f32x4 acc[2][4] = {};
    gemm32(As, wbf + 3*65536, cw, lrow, kg8, acc);

    #pragma unroll
    for (int j = 0; j < 4; ++j) {
        const int ch = cw + j*16 + ccol;
        const float bias_v = bo[ch];
        #pragma unroll
        for (int i = 0; i < 2; ++i)
            #pragma unroll
            for (int r = 0; r < 4; ++r) {
                const int row = i*16 + crow0 + r;
                const size_t g = (size_t)(r0 + row) * C_ + ch;
                out[g] = acc[i][j][r] + bias_v + query[g];
            }
    }
}

// ---------------------------------------------------------------------------
extern "C" void kernel_launch(void* const* d_in, const int* in_sizes, int n_in,
                              void* d_out, int out_size, void* d_ws, size_t ws_size,
                              hipStream_t stream)
{
    const float* query = (const float*)d_in[0];
    const float* key   = (const float*)d_in[1];
    const float* qpos  = (const float*)d_in[2];
    const float* kpos  = (const float*)d_in[3];
    const float* Wq = (const float*)d_in[4];  const float* bq = (const float*)d_in[5];
    const float* Wk = (const float*)d_in[6];  const float* bk = (const float*)d_in[7];
    const float* Wv = (const float*)d_in[8];  const float* bv = (const float*)d_in[9];
    const float* Wo = (const float*)d_in[10]; const float* bo = (const float*)d_in[11];

    unsigned short* wbf = (unsigned short*)d_ws;        // 4*65536 bf16 = 512 KB
    unsigned short* abf = wbf + 4*65536;                // B*N*C bf16 = 3.7 MB
    float* out = (float*)d_out;

    pack_w<<<128, 256, 0, stream>>>(Wq, Wk, Wv, Wo, wbf);
    fused_qkva<<<NBLK, 256, LDS1, stream>>>(query, key, qpos, kpos, wbf,
                                            bq, bk, bv, abf);
    outproj<<<NBLK, 256, 0, stream>>>(abf, wbf, bo, query, out);
}

// Round 5
// 51.259 us; speedup vs baseline: 5.2989x; 1.0381x over previous
//
#include <hip/hip_runtime.h>
#include <math.h>

#define EPSV 1e-6f
constexpr int N_ = 900, B_ = 8, C_ = 256, H_ = 8, D_ = 32;
constexpr int M_TOT = N_ * B_;        // 7200 rows
constexpr int BM1 = 16;               // rows per block, kernel 1
constexpr int NBLK1 = M_TOT / BM1;    // 450 blocks
constexpr int BM2 = 32;               // rows per block, kernel 2
constexpr int NBLK2 = M_TOT / BM2;    // 225 row-blocks (x2 col-halves)

typedef __attribute__((ext_vector_type(8))) short short8;       // 8 bf16
typedef __attribute__((ext_vector_type(4))) float f32x4;
typedef __attribute__((ext_vector_type(2))) float f32x2;
typedef __attribute__((ext_vector_type(2))) unsigned short us2;

__device__ __forceinline__ unsigned short f2bf(float f) {   // RNE fp32->bf16
    unsigned int u = __float_as_uint(f);
    return (unsigned short)((u + 0x7FFFu + ((u >> 16) & 1u)) >> 16);
}
// swizzled byte offset in a [rows]x256-bf16 LDS tile (row stride 512B)
__device__ __forceinline__ int swz(int row, int kElem) {
    int b = (row << 9) + (kElem << 1);
    return b ^ ((row & 7) << 4);
}
__device__ __forceinline__ float red16(float v) {  // sum over 16-lane group
    v += __shfl_xor(v, 1); v += __shfl_xor(v, 2);
    v += __shfl_xor(v, 4); v += __shfl_xor(v, 8);
    return v;
}

// ---------------------------------------------------------------------------
// prep: pack Wq|Wk|Wv|Wo (fp32 row-major 256x256) -> bf16, concatenated.
// ---------------------------------------------------------------------------
__global__ __launch_bounds__(256)
void pack_w(const float* __restrict__ Wq, const float* __restrict__ Wk,
            const float* __restrict__ Wv, const float* __restrict__ Wo,
            unsigned short* __restrict__ wbf)
{
    const int i = (blockIdx.x * 256 + threadIdx.x) * 8;
    const float* src = (i < 65536) ? Wq : (i < 131072) ? Wk : (i < 196608) ? Wv : Wo;
    const int off = i & 65535;
    const float4 a = *reinterpret_cast<const float4*>(src + off);
    const float4 b = *reinterpret_cast<const float4*>(src + off + 4);
    short8 p;
    p[0]=(short)f2bf(a.x); p[1]=(short)f2bf(a.y); p[2]=(short)f2bf(a.z); p[3]=(short)f2bf(a.w);
    p[4]=(short)f2bf(b.x); p[5]=(short)f2bf(b.y); p[6]=(short)f2bf(b.z); p[7]=(short)f2bf(b.w);
    *reinterpret_cast<short8*>(wbf + i) = p;
}

// ---------------------------------------------------------------------------
// 16-row x 256-col GEMM: A from swizzled LDS (bf16), W bf16 from global (L2).
// Wave owns 64 cols, 1x4 frags, K=256 unrolled -> 32 MFMA.
// ---------------------------------------------------------------------------
__device__ __forceinline__ void gemm16(const unsigned char* As,
                                       const unsigned short* Wg,
                                       int cw, int lrow, int kg8,
                                       f32x4 acc[4])
{
    #pragma unroll
    for (int kk = 0; kk < C_; kk += 32) {
        const short8 af = *reinterpret_cast<const short8*>(As + swz(lrow, kk + kg8));
        #pragma unroll
        for (int j = 0; j < 4; ++j) {
            const short8 bf = *reinterpret_cast<const short8*>(
                Wg + (size_t)(cw + j*16 + lrow) * C_ + kk + kg8);
            acc[j] = __builtin_amdgcn_mfma_f32_16x16x32_bf16(af, bf, acc[j], 0, 0, 0);
        }
    }
}

// ---------------------------------------------------------------------------
// Kernel 1: fused q/k/v projections + head-axis attention, 16 rows/block.
// attn out -> bf16 flat (B,H,N,D): b*230400 + h*28800 + n*32 + d.
// ---------------------------------------------------------------------------
constexpr int QS = 264;                                    // fp32 row stride
constexpr int LDS1 = 8192*2 + 3 * BM1 * QS * 4;            // 67072 bytes

__global__ __launch_bounds__(256, 2)
void fused_qkva(const float* __restrict__ query, const float* __restrict__ key,
                const float* __restrict__ qpos,  const float* __restrict__ kpos,
                const unsigned short* __restrict__ wbf,
                const float* __restrict__ bq, const float* __restrict__ bk,
                const float* __restrict__ bv,
                unsigned short* __restrict__ abf)
{
    extern __shared__ char smem[];
    unsigned char* Aq = (unsigned char*)smem;            // 8 KB
    unsigned char* Ak = (unsigned char*)smem + 8192;     // 8 KB
    float* q_s = (float*)(smem + 16384);                 // [16][264]
    float* k_s = q_s + BM1 * QS;
    float* v_s = k_s + BM1 * QS;

    const int tid = threadIdx.x;
    const int r0  = blockIdx.x * BM1;

    // ---- phase 0: stage query/key rows -> bf16 swizzled LDS ----
    {
        const int trow = tid >> 5, k0 = (tid & 31) * 8;
        #pragma unroll
        for (int i = 0; i < 2; ++i) {
            const int row = trow + i * 8;
            const float* xr = query + (size_t)(r0 + row) * C_ + k0;
            const float4 a0 = *reinterpret_cast<const float4*>(xr);
            const float4 a1 = *reinterpret_cast<const float4*>(xr + 4);
            short8 pa;
            pa[0]=(short)f2bf(a0.x); pa[1]=(short)f2bf(a0.y);
            pa[2]=(short)f2bf(a0.z); pa[3]=(short)f2bf(a0.w);
            pa[4]=(short)f2bf(a1.x); pa[5]=(short)f2bf(a1.y);
            pa[6]=(short)f2bf(a1.z); pa[7]=(short)f2bf(a1.w);
            *reinterpret_cast<short8*>(Aq + swz(row, k0)) = pa;
            const float* kr = key + (size_t)(r0 + row) * C_ + k0;
            const float4 b0 = *reinterpret_cast<const float4*>(kr);
            const float4 b1 = *reinterpret_cast<const float4*>(kr + 4);
            short8 pb;
            pb[0]=(short)f2bf(b0.x); pb[1]=(short)f2bf(b0.y);
            pb[2]=(short)f2bf(b0.z); pb[3]=(short)f2bf(b0.w);
            pb[4]=(short)f2bf(b1.x); pb[5]=(short)f2bf(b1.y);
            pb[6]=(short)f2bf(b1.z); pb[7]=(short)f2bf(b1.w);
            *reinterpret_cast<short8*>(Ak + swz(row, k0)) = pb;
        }
    }
    __syncthreads();

    const int wave = tid >> 6, lane = tid & 63;
    const int cw = wave * 64;
    const int lrow = lane & 15, kg8 = (lane >> 4) * 8;
    const int crow0 = (lane >> 4) * 4, ccol = lane & 15;

    // ---- phase 1: q/k/v GEMMs -> LDS fp32 (sigmoid on q,k) ----
    {
        f32x4 acc[4] = {};
        gemm16(Aq, wbf + 0*65536, cw, lrow, kg8, acc);
        #pragma unroll
        for (int j = 0; j < 4; ++j) {
            const int ch = cw + j*16 + ccol;
            const float bias_v = bq[ch];
            #pragma unroll
            for (int r = 0; r < 4; ++r) {
                const int row = crow0 + r;
                float v = acc[j][r] + bias_v + qpos[(size_t)(r0+row)*C_ + ch];
                q_s[row*QS + ch] = 1.f / (1.f + expf(-v));
            }
        }
    }
    {
        f32x4 acc[4] = {};
        gemm16(Ak, wbf + 1*65536, cw, lrow, kg8, acc);
        #pragma unroll
        for (int j = 0; j < 4; ++j) {
            const int ch = cw + j*16 + ccol;
            const float bias_v = bk[ch];
            #pragma unroll
            for (int r = 0; r < 4; ++r) {
                const int row = crow0 + r;
                float v = acc[j][r] + bias_v + kpos[(size_t)(r0+row)*C_ + ch];
                k_s[row*QS + ch] = 1.f / (1.f + expf(-v));
            }
        }
    }
    {
        f32x4 acc[4] = {};
        gemm16(Ak, wbf + 2*65536, cw, lrow, kg8, acc);
        #pragma unroll
        for (int j = 0; j < 4; ++j) {
            const int ch = cw + j*16 + ccol;
            const float bias_v = bv[ch];
            #pragma unroll
            for (int r = 0; r < 4; ++r) {
                const int row = crow0 + r;
                v_s[row*QS + ch] = acc[j][r] + bias_v;
            }
        }
    }
    __syncthreads();

    // ---- phase 2: per-location attention, 16 threads/location ----
    {
        const int loc = tid >> 4, tt = tid & 15, d0 = tt * 2;
        const int gr = r0 + loc;                 // global row in (n,b) order
        const int nn = gr >> 3, bb = gr & 7;
        const float* qr = q_s + loc * QS + d0;
        const float* kr = k_s + loc * QS + d0;
        const float* vr = v_s + loc * QS + d0;
        f32x2 qh[8], kh[8], vh[8];
        #pragma unroll
        for (int h = 0; h < 8; ++h) {
            qh[h] = *reinterpret_cast<const f32x2*>(qr + h*32);
            kh[h] = *reinterpret_cast<const f32x2*>(kr + h*32);
            vh[h] = *reinterpret_cast<const f32x2*>(vr + h*32);
        }

        float ir1[8], so_[8];
        {
            f32x2 ck = {0,0}, cq = {0,0};
            #pragma unroll
            for (int h = 0; h < 8; ++h) {
                float p1 = 0.f, p2 = 0.f;
                #pragma unroll
                for (int j = 0; j < 2; ++j) {
                    ck[j] += kh[h][j]; cq[j] += qh[h][j];
                    p1 += (qh[h][j] + EPSV) * (ck[j] + EPSV);
                    p2 += (kh[h][j] + EPSV) * (cq[j] + EPSV);
                }
                p1 = red16(p1); p2 = red16(p2);
                ir1[h] = 1.f / p1;
                so_[h] = (float)(h+1) / p2;
            }
        }
        float salloc[8], scomp[8];
        {
            f32x2 c2 = {0,0}, c3 = {0,0};
            float css = 0.f;
            #pragma unroll
            for (int h = 0; h < 8; ++h) {
                const float sih = (float)(h+1) * ir1[h];
                float p3 = 0.f, p4 = 0.f;
                #pragma unroll
                for (int j = 0; j < 2; ++j) {
                    c2[j] += kh[h][j] * so_[h];
                    c3[j] += qh[h][j] * sih;
                    p3 += (qh[h][j] + EPSV) * (c2[j] + EPSV);
                    p4 += (kh[h][j] + EPSV) * (c3[j] + EPSV);
                }
                p3 = red16(p3); p4 = red16(p4);
                const float inv_n = 1.f / (float)(h+1);
                salloc[h] = 1.f / (1.f + expf(-p3 * inv_n));
                const float consrc = fminf(1.f, fmaxf(-1.f, p4 * inv_n));
                const float cs = expf(consrc);
                css += cs;
                scomp[h] = cs / css * (float)(h+1);
            }
        }
        // qkv + store to global flat (B,H,N,D) as bf16
        #pragma unroll
        for (int h = 0; h < 8; ++h) {
            f32x2 qs2, a2 = {0,0};
            #pragma unroll
            for (int j = 0; j < 2; ++j) qs2[j] = qh[h][j] * ir1[h];
            #pragma unroll
            for (int h2 = 0; h2 <= h; ++h2) {
                float p = 0.f;
                #pragma unroll
                for (int j = 0; j < 2; ++j) p += qs2[j] * kh[h2][j];
                p = red16(p);
                const float w = p * scomp[h2];
                #pragma unroll
                for (int j = 0; j < 2; ++j) a2[j] += w * vh[h2][j];
            }
            us2 o;
            o[0] = f2bf(a2[0] * salloc[h]);
            o[1] = f2bf(a2[1] * salloc[h]);
            *reinterpret_cast<us2*>(abf + (size_t)bb*(H_*N_*D_) + (size_t)h*(N_*D_)
                                        + (size_t)nn*D_ + d0) = o;
        }
    }
}

// ---------------------------------------------------------------------------
// Kernel 2: out-projection + residual, col-split: block = 32 rows x 128 cols.
// A rows are the SCRAMBLED flat slices: out row gr=(n*B+b) reads
// abf[b*N*C + n*256 .. +255] (bf16 copy).
// ---------------------------------------------------------------------------
__global__ __launch_bounds__(256, 2)
void outproj(const unsigned short* __restrict__ abf,
             const unsigned short* __restrict__ wbf,
             const float* __restrict__ bo,
             const float* __restrict__ query,
             float* __restrict__ out)
{
    __shared__ unsigned char As[16384];
    const int tid = threadIdx.x;
    const int r0  = blockIdx.x * BM2;
    const int c0  = blockIdx.y * 128;

    {   // stage scrambled A rows (pure bf16 copy)
        const int trow = tid >> 5, k0 = (tid & 31) * 8;
        #pragma unroll
        for (int i = 0; i < 4; ++i) {
            const int row = trow + i * 8;
            const int gr = r0 + row;
            const int nn = gr >> 3, bb = gr & 7;
            const short8 p = *reinterpret_cast<const short8*>(
                abf + (size_t)bb * (N_*C_) + (size_t)nn * C_ + k0);
            *reinterpret_cast<short8*>(As + swz(row, k0)) = p;
        }
    }
    __syncthreads();

    const int wave = tid >> 6, lane = tid & 63;
    const int cw = c0 + wave * 32;
    const int lrow = lane & 15, kg8 = (lane >> 4) * 8;
    const int crow0 = (lane >> 4) * 4, ccol = lane & 15;
    const unsigned short* Wg = wbf + 3*65536;

    f32x4 acc[2][2] = {};
    #pragma unroll
    for (int kk = 0; kk < C_; kk += 32) {
        const short8 af0 = *reinterpret_cast<const short8*>(As + swz(lrow,      kk + kg8));
        const short8 af1 = *reinterpret_cast<const short8*>(As + swz(16 + lrow, kk + kg8));
        #pragma unroll
        for (int j = 0; j < 2; ++j) {
            const short8 bf = *reinterpret_cast<const short8*>(
                Wg + (size_t)(cw + j*16 + lrow) * C_ + kk + kg8);
            acc[0][j] = __builtin_amdgcn_mfma_f32_16x16x32_bf16(af0, bf, acc[0][j], 0, 0, 0);
            acc[1][j] = __builtin_amdgcn_mfma_f32_16x16x32_bf16(af1, bf, acc[1][j], 0, 0, 0);
        }
    }

    #pragma unroll
    for (int j = 0; j < 2; ++j) {
        const int ch = cw + j*16 + ccol;
        const float bias_v = bo[ch];
        #pragma unroll
        for (int i = 0; i < 2; ++i)
            #pragma unroll
            for (int r = 0; r < 4; ++r) {
                const int row = i*16 + crow0 + r;
                const size_t g = (size_t)(r0 + row) * C_ + ch;
                out[g] = acc[i][j][r] + bias_v + query[g];
            }
    }
}

// ---------------------------------------------------------------------------
extern "C" void kernel_launch(void* const* d_in, const int* in_sizes, int n_in,
                              void* d_out, int out_size, void* d_ws, size_t ws_size,
                              hipStream_t stream)
{
    const float* query = (const float*)d_in[0];
    const float* key   = (const float*)d_in[1];
    const float* qpos  = (const float*)d_in[2];
    const float* kpos  = (const float*)d_in[3];
    const float* Wq = (const float*)d_in[4];  const float* bq = (const float*)d_in[5];
    const float* Wk = (const float*)d_in[6];  const float* bk = (const float*)d_in[7];
    const float* Wv = (const float*)d_in[8];  const float* bv = (const float*)d_in[9];
    const float* Wo = (const float*)d_in[10]; const float* bo = (const float*)d_in[11];

    unsigned short* wbf = (unsigned short*)d_ws;        // 4*65536 bf16 = 512 KB
    unsigned short* abf = wbf + 4*65536;                // B*N*C bf16 = 3.7 MB
    float* out = (float*)d_out;

    pack_w<<<128, 256, 0, stream>>>(Wq, Wk, Wv, Wo, wbf);
    fused_qkva<<<NBLK1, 256, LDS1, stream>>>(query, key, qpos, kpos, wbf,
                                             bq, bk, bv, abf);
    outproj<<<dim3(NBLK2, 2), 256, 0, stream>>>(abf, wbf, bo, query, out);
}